// Round 12
// baseline (1611.762 us; speedup 1.0000x reference)
//
#include <hip/hip_runtime.h>

#define N_Q   65536
#define N_C   2048
#define KNN_K 16
#define CDIM  64
#define SLCAP 128
#define KINF  0x7FFFFFFF
#define WSZ   108544  // halves per weight image

typedef _Float16 half_t;
typedef float v4f __attribute__((ext_vector_type(4)));
typedef half_t v8h __attribute__((ext_vector_type(8)));

#define ASTRIDE 136   // 128 + 8 pad (halves); row = 272 B = 17*16 B
#define DSTRIDE 40    // 32 + 8 pad

// ---------------------------------------------------------------------------
// Kernel 0: weights -> fp16 MFMA-fragment-order tiles + cpos4 = (x,y,z,|c|^2+4)
// Tile (16 cols x 32 k) = 512 contiguous halves; element = lane*8+j,
// lane = (n&15)+16*quad, k = k0*32 + quad*8 + j. Tiles ordered [k0][tcol].
// ---------------------------------------------------------------------------
__global__ void wtrans_kernel(const float* W0, const float* W1, const float* W2,
                              const float* W3, const float* Wf, const float* Wd,
                              const int* indices, const float* cpos,
                              half_t* wt, float4* cpos4){
  int idx = blockIdx.x * 256 + threadIdx.x;
  if (idx >= 110592) return;
  if (idx >= WSZ){
    int i = idx - WSZ;
    const float* cp = cpos + (size_t)indices[0] * N_C * 3;
    float x = cp[i*3 + 0], y = cp[i*3 + 1], z = cp[i*3 + 2];
    cpos4[i] = make_float4(x, y, z, fmaf(x, x, fmaf(y, y, fmaf(z, z, 4.0f))));
    return;
  }
  int base, nt, mode;            // mode: 0 plain(src), 1 W0, 2 W2, 3 Wd
  const float* src = W1;
  if (idx < 16384){ base = 0; nt = 8; mode = 1; }
  else if (idx < 32768){ base = 16384; nt = 8; mode = 0; src = W1; }
  else if (idx < 65536){ base = 32768; nt = 8; mode = 2; }
  else if (idx < 81920){ base = 65536; nt = 8; mode = 0; src = W3; }
  else if (idx < 98304){ base = 81920; nt = 8; mode = 0; src = Wf; }
  else { base = 98304; nt = 4; mode = 3; }
  int i = idx - base;
  int tile = i >> 9, e = i & 511;
  int lane = e >> 3, j = e & 7;
  int k0idx = tile / nt, tcol = tile - k0idx*nt;
  int n = tcol*16 + (lane & 15);
  int k = k0idx*32 + ((lane >> 4) << 3) + j;
  float val;
  if (mode == 0)      val = src[k*128 + n];
  else if (mode == 1) val = (k < 127) ? W0[k*128 + n] : 0.f;
  else if (mode == 2) val = (k == 127) ? 0.f
                           : ((k < 127) ? W2[k*128 + n] : W2[(k-1)*128 + n]);
  else                val = (k < 155) ? Wd[k*64 + n] : 0.f;
  wt[idx] = (half_t)val;
}

// ---------------------------------------------------------------------------
// B-fragments from global in fragment order (one coalesced 1 KB load/tile).
// ---------------------------------------------------------------------------
template<int NT>
__device__ inline void mfma_sw(const half_t* act, int astride, int rowbase,
                               const half_t* wlayer, int nt, int ktbase,
                               int tcolbase, int kchunk, v4f* acc, int lane){
  int m = lane & 15, quad = lane >> 4;
#pragma unroll
  for (int k0 = 0; k0 < kchunk; k0 += 32){
    v8h a = *(const v8h*)&act[(rowbase + m)*astride + k0 + quad*8];
    int krow = ktbase + (k0 >> 5);
#pragma unroll
    for (int t = 0; t < NT; t++){
      const half_t* bp = wlayer + ((size_t)((krow*nt + tcolbase + t) << 9) + (lane << 3));
      v8h b = *(const v8h*)bp;
      acc[t] = __builtin_amdgcn_mfma_f32_16x16x32_f16(a, b, acc[t], 0, 0, 0);
    }
  }
}

template<int NT>
__device__ inline void epilogue(v4f* acc, half_t* outb, int rowbase, int colbase,
                                const float* bias, bool relu, int lane){
  int n = lane & 15, quad = lane >> 4;
#pragma unroll
  for (int t = 0; t < NT; t++){
    int col = colbase + t*16 + n;
    float bv = bias[col];
#pragma unroll
    for (int r = 0; r < 4; r++){
      float v = acc[t][r] + bv;
      if (relu) v = fmaxf(v, 0.f);
      outb[(rowbase + quad*4 + r)*ASTRIDE + col] = (half_t)v;
    }
  }
}

// ---------------------------------------------------------------------------
// Fused kernel: per block (512 thr = 8 waves) handle 32 queries end-to-end.
// Phase 1 (knn): each wave does 4 queries sequentially (round-9 exact
//   tau-pruned selection, 32-VGPR working set reused per query — the qi loop
//   is unroll-1 on purpose; unrolling would spill like round 10).
// Phase 2 (mlp): 8 waves, each 16 rows x 32 cols (NT=2; Wd NT=1).
// LDS aliasing: lp(32K)+sl(4K) die at the phase barrier; Pbuf/Qbuf overlay
//   lp's region. Abuf/Dbuf live across the boundary. Total 47.1 KB ->
//   3 blocks/CU = 24 waves (75%), mixing VALU-heavy and latency-heavy phases.
// ---------------------------------------------------------------------------
__global__ __launch_bounds__(512, 6) void fused_kernel(const int* indices,
    const float* qpts, const float4* cpos4, const float* codes,
    const float* xyzdir, const half_t* wt,
    const float* b0, const float* b1, const float* b2, const float* b3,
    const float* bfb, const float* bdb,
    const float* Wsb, const float* bsb, const float* Wrb, const float* brb,
    float* out){
  __shared__ __align__(16) char smem[48128];
  float4* lp   = (float4*)smem;                 // [0, 32768)   knn
  half_t* Pbuf = (half_t*)smem;                 // [0, 8704)    mlp (alias lp)
  half_t* Qbuf = (half_t*)(smem + 16384);       // [16384,25088) mlp (alias lp)
  int*    sl   = (int*)(smem + 32768);          // [32768,36864) knn
  half_t* Abuf = (half_t*)(smem + 36864);       // [36864,45568) both
  half_t* Dbuf = (half_t*)(smem + 45568);       // [45568,48128) both

  int tid = threadIdx.x;
  int lane = tid & 63, wave = tid >> 6;
  int l = lane & 15;
  int qbase = blockIdx.x * 32;
  const float* cc = codes + (size_t)indices[0] * N_C * CDIM;

  for (int c = tid; c < N_C; c += 512) lp[c] = cpos4[c];
  __syncthreads();

  // ---------------- Phase 1: exact 16-NN, 4 queries per wave ----------------
#pragma unroll 1
  for (int qi = 0; qi < 4; qi++){
    int lq = wave * 4 + qi;            // local query 0..31
    int q  = qbase + lq;
    float qx = qpts[q*3 + 0];
    float qy = qpts[q*3 + 1];
    float qz = qpts[q*3 + 2];
    float nqx = -2.0f*qx, nqy = -2.0f*qy, nqz = -2.0f*qz;

    int p[32];
#pragma unroll
    for (int j = 0; j < 32; j++){
      int c = j*64 + lane;
      float4 P = lp[c];
      float s = fmaf(P.x, nqx, fmaf(P.y, nqy, fmaf(P.z, nqz, P.w)));  // > 0
      p[j] = (__float_as_int(s) & 0xFFFFF800) | c;
    }

    int lm = p[0];
#pragma unroll
    for (int j = 1; j < 32; j++) lm = min(lm, p[j]);

    // sort lane-mins within 16-lane groups (10 stages)
    int v = lm;
#pragma unroll
    for (int k = 2; k <= 16; k <<= 1){
#pragma unroll
      for (int j = k >> 1; j > 0; j >>= 1){
        int o = __shfl_xor(v, j, 64);
        bool dirDesc = (l & k) != 0;
        bool lower   = (l & j) == 0;
        int mn = min(v, o), mx = max(v, o);
        v = (lower != dirDesc) ? mn : mx;
      }
    }
    int t0 = __shfl(v, 3, 64),  t1 = __shfl(v, 19, 64);
    int t2 = __shfl(v, 35, 64), t3 = __shfl(v, 51, 64);
    int tau = max(max(t0, t1), max(t2, t3));   // guarantees nsurv >= 16

    // ballot-compaction into wave-private LDS list
    int* slw = &sl[wave * SLCAP];
    int nsurv = 0;
#pragma unroll
    for (int j = 0; j < 32; j++){
      bool c = (p[j] <= tau);
      unsigned long long m = __ballot(c);
      if (m){
        if (nsurv <= 64){
          if (c){
            int mb = __builtin_amdgcn_mbcnt_hi((unsigned)(m >> 32),
                     __builtin_amdgcn_mbcnt_lo((unsigned)m, 0));
            slw[nsurv + mb] = p[j];
          }
        }
        nsurv += (int)__popcll(m);
      }
    }
    __builtin_amdgcn_wave_barrier();

    int keep;
    if (nsurv >= KNN_K && nsurv <= 64){
      // top-16-of-64 selection network -> lanes 0..15 hold the top-16 set
      int x = (lane < nsurv) ? slw[lane] : KINF;
#pragma unroll
      for (int k = 2; k <= 16; k <<= 1){
#pragma unroll
        for (int j = k >> 1; j > 0; j >>= 1){
          int o = __shfl_xor(x, j, 64);
          bool dirDesc = (l & k) != 0;
          bool lower   = (l & j) == 0;
          int mn = min(x, o), mx = max(x, o);
          x = (lower != dirDesc) ? mn : mx;
        }
      }
      x = min(x, __shfl_xor(x, 31, 64));
#pragma unroll
      for (int j = 8; j > 0; j >>= 1){
        int o = __shfl_xor(x, j, 64);
        bool lower = (l & j) == 0;
        int mn = min(x, o), mx = max(x, o);
        x = lower ? mn : mx;
      }
      x = min(x, __shfl_xor(x, 63, 64));
      keep = x;
    } else {
      // exact fallback: full rescan extraction over p[32] (rare)
      keep = KINF;
#pragma unroll 1
      for (int rr = 0; rr < KNN_K; rr++){
        int lmf = p[0];
#pragma unroll
        for (int j = 1; j < 32; j++) lmf = min(lmf, p[j]);
        int gm = lmf;
#pragma unroll
        for (int off2 = 1; off2 < 64; off2 <<= 1)
          gm = min(gm, __shfl_xor(gm, off2, 64));
        if (lane == rr) keep = gm;
#pragma unroll
        for (int j = 0; j < 32; j++) p[j] = (p[j] == gm) ? KINF : p[j];
      }
    }

    // exact d2 + inverse-d2 weights (lanes 0..15 meaningful)
    int ci = keep & 0x7FF;
    float4 P = lp[ci];
    float dx = qx - P.x, dy = qy - P.y, dz = qz - P.z;
    float d2 = fmaf(dz, dz, fmaf(dy, dy, dx*dx));
    float w = 1.0f / (d2 + 1e-16f);
    float wm = (lane < KNN_K) ? w : 0.0f;
#pragma unroll
    for (int off2 = 1; off2 < 64; off2 <<= 1) wm += __shfl_xor(wm, off2, 64);
    float wn = w / wm;

    float acc = 0.f;
#pragma unroll
    for (int i = 0; i < KNN_K; i++){
      int   cb = __shfl(ci, i, 64);
      float wb = __shfl(wn, i, 64);
      acc = fmaf(wb, cc[cb*CDIM + lane], acc);
    }
    int arow = lq * ASTRIDE;
    Abuf[arow + lane] = (half_t)acc;

    // activation staging: xyzdir -> Abuf cols 64..135 (with pads) and Dbuf
    float xv = (lane < 63) ? xyzdir[(size_t)q*90 + lane] : 0.f;
    Abuf[arow + 64 + lane] = (half_t)xv;
    if (lane < 8) Abuf[arow + 128 + lane] = (half_t)0.f;
    if (lane < 40){
      float dv = (lane < 27) ? xyzdir[(size_t)q*90 + 63 + lane] : 0.f;
      Dbuf[lq*DSTRIDE + lane] = (half_t)dv;
    }
  }
  __syncthreads();   // phase boundary: lp/sl dead; Pbuf/Qbuf may be written

  // ---------------- Phase 2: MFMA MLP, 8 waves x (16 rows x 32 cols) -------
  int rowbase  = (wave >> 2) * 16;
  int colq     = wave & 3;
  int colbase  = colq * 32;
  int tcolbase = colq * 2;
  v4f acc[2];

  const half_t* wt0 = wt;
  const half_t* wt1 = wt + 16384;
  const half_t* wt2 = wt + 32768;
  const half_t* wt3 = wt + 65536;
  const half_t* wtf = wt + 81920;
  const half_t* wtd = wt + 98304;

#define ZACC2() { for (int t_ = 0; t_ < 2; t_++) for (int e_ = 0; e_ < 4; e_++) acc[t_][e_] = 0.f; }

  // L0: A @ W0 -> P (relu)
  ZACC2();
  mfma_sw<2>(Abuf, ASTRIDE, rowbase, wt0, 8, 0, tcolbase, 128, acc, lane);
  epilogue<2>(acc, Pbuf, rowbase, colbase, b0, true, lane);
  __syncthreads();

  // L1: P @ W1 -> Q (relu)
  ZACC2();
  mfma_sw<2>(Pbuf, ASTRIDE, rowbase, wt1, 8, 0, tcolbase, 128, acc, lane);
  epilogue<2>(acc, Qbuf, rowbase, colbase, b1, true, lane);
  __syncthreads();

  // L2: [input_xyz | h1] @ W2 -> P (relu)   (K = 256)
  ZACC2();
  mfma_sw<2>(Abuf, ASTRIDE, rowbase, wt2, 8, 0, tcolbase, 128, acc, lane);
  mfma_sw<2>(Qbuf, ASTRIDE, rowbase, wt2, 8, 4, tcolbase, 128, acc, lane);
  epilogue<2>(acc, Pbuf, rowbase, colbase, b2, true, lane);
  __syncthreads();

  // L3: P @ W3 -> A (h3, kept for sigma; input_xyz dead)
  ZACC2();
  mfma_sw<2>(Pbuf, ASTRIDE, rowbase, wt3, 8, 0, tcolbase, 128, acc, lane);
  epilogue<2>(acc, Abuf, rowbase, colbase, b3, true, lane);
  __syncthreads();

  // Wf: A(h3) @ Wf -> P (no relu)
  ZACC2();
  mfma_sw<2>(Abuf, ASTRIDE, rowbase, wtf, 8, 0, tcolbase, 128, acc, lane);
  epilogue<2>(acc, Pbuf, rowbase, colbase, bfb, false, lane);
  __syncthreads();

  // Wd: [P(final) | D(dir)] @ Wd -> Q[:,0:64] (relu); nt=4, NT=1, tile = colq
  ZACC2();
  mfma_sw<1>(Pbuf, ASTRIDE, rowbase, wtd, 4, 0, colq, 128, acc, lane);
  mfma_sw<1>(Dbuf, DSTRIDE, rowbase, wtd, 4, 4, colq,  32, acc, lane);
  epilogue<1>(acc, Qbuf, rowbase, colq * 16, bdb, true, lane);
  __syncthreads();

  // Tail: sigma = h3(Abuf).Ws + bs ; rgb = d(Qbuf).Wr + br  (16 thr/query)
  {
    int q = tid >> 4, part = tid & 15;
    float s = 0.f;
#pragma unroll
    for (int k = 0; k < 8; k++){
      int kk = part*8 + k;
      s = fmaf((float)Abuf[q*ASTRIDE + kk], Wsb[kk], s);
    }
    s += __shfl_xor(s, 1, 64); s += __shfl_xor(s, 2, 64);
    s += __shfl_xor(s, 4, 64); s += __shfl_xor(s, 8, 64);

    float r3[3];
#pragma unroll
    for (int c2 = 0; c2 < 3; c2++){
      float rv = 0.f;
#pragma unroll
      for (int k = 0; k < 4; k++){
        int kk = part*4 + k;
        rv = fmaf((float)Qbuf[q*ASTRIDE + kk], Wrb[kk*3 + c2], rv);
      }
      rv += __shfl_xor(rv, 1, 64); rv += __shfl_xor(rv, 2, 64);
      rv += __shfl_xor(rv, 4, 64); rv += __shfl_xor(rv, 8, 64);
      r3[c2] = rv;
    }
    if (part == 0){
      size_t ob = ((size_t)(qbase + q)) * 4;
      out[ob + 0] = r3[0] + brb[0];
      out[ob + 1] = r3[1] + brb[1];
      out[ob + 2] = r3[2] + brb[2];
      out[ob + 3] = s + bsb[0];
    }
  }
}

// ---------------------------------------------------------------------------
extern "C" void kernel_launch(void* const* d_in, const int* in_sizes, int n_in,
                              void* d_out, int out_size, void* d_ws, size_t ws_size,
                              hipStream_t stream){
  (void)in_sizes; (void)n_in; (void)out_size; (void)ws_size;

  const int*   indices = (const int*)d_in[0];
  const float* qpts    = (const float*)d_in[1];
  const float* xyzdir  = (const float*)d_in[2];
  const float* cpos    = (const float*)d_in[3];
  const float* codes   = (const float*)d_in[4];
  const float* W0 = (const float*)d_in[5];
  const float* b0 = (const float*)d_in[6];
  const float* W1 = (const float*)d_in[7];
  const float* b1 = (const float*)d_in[8];
  const float* W2 = (const float*)d_in[9];
  const float* b2 = (const float*)d_in[10];
  const float* W3 = (const float*)d_in[11];
  const float* b3 = (const float*)d_in[12];
  const float* Wf = (const float*)d_in[13];
  const float* bf = (const float*)d_in[14];
  const float* Wd = (const float*)d_in[15];
  const float* bd = (const float*)d_in[16];
  const float* Ws = (const float*)d_in[17];
  const float* bs = (const float*)d_in[18];
  const float* Wr = (const float*)d_in[19];
  const float* br = (const float*)d_in[20];

  // ws layout: wt | cpos4
  half_t* wt    = (half_t*)d_ws;                          // 217,088 B
  float4* cpos4 = (float4*)((char*)d_ws + 217088);        //  32,768 B

  wtrans_kernel<<<(110592 + 255)/256, 256, 0, stream>>>(W0, W1, W2, W3, Wf, Wd,
                                                        indices, cpos, wt, cpos4);
  fused_kernel<<<N_Q/32, 512, 0, stream>>>(indices, qpts, cpos4, codes, xyzdir,
                                           wt, b0, b1, b2, b3, bf, bd,
                                           Ws, bs, Wr, br, (float*)d_out);
}

// Round 13
// 371.655 us; speedup vs baseline: 4.3367x; 4.3367x over previous
//
#include <hip/hip_runtime.h>

#define N_Q   65536
#define N_C   2048
#define KNN_K 16
#define CDIM  64
#define SLCAP 128
#define KINF  0x7FFFFFFF
#define WSZ   108544  // halves per weight image

typedef _Float16 half_t;
typedef float v4f __attribute__((ext_vector_type(4)));
typedef half_t v8h __attribute__((ext_vector_type(8)));

#define ASTRIDE 136   // 128 + 8 pad (halves); row = 272 B = 17*16 B
#define DSTRIDE 40    // 32 + 8 pad

// ---------------------------------------------------------------------------
// Kernel 0: weights -> fp16 MFMA-fragment-order tiles + cpos4 = (x,y,z,|c|^2+4)
// ---------------------------------------------------------------------------
__global__ void wtrans_kernel(const float* W0, const float* W1, const float* W2,
                              const float* W3, const float* Wf, const float* Wd,
                              const int* indices, const float* cpos,
                              half_t* wt, float4* cpos4){
  int idx = blockIdx.x * 256 + threadIdx.x;
  if (idx >= 110592) return;
  if (idx >= WSZ){
    int i = idx - WSZ;
    const float* cp = cpos + (size_t)indices[0] * N_C * 3;
    float x = cp[i*3 + 0], y = cp[i*3 + 1], z = cp[i*3 + 2];
    cpos4[i] = make_float4(x, y, z, fmaf(x, x, fmaf(y, y, fmaf(z, z, 4.0f))));
    return;
  }
  int base, nt, mode;            // mode: 0 plain(src), 1 W0, 2 W2, 3 Wd
  const float* src = W1;
  if (idx < 16384){ base = 0; nt = 8; mode = 1; }
  else if (idx < 32768){ base = 16384; nt = 8; mode = 0; src = W1; }
  else if (idx < 65536){ base = 32768; nt = 8; mode = 2; }
  else if (idx < 81920){ base = 65536; nt = 8; mode = 0; src = W3; }
  else if (idx < 98304){ base = 81920; nt = 8; mode = 0; src = Wf; }
  else { base = 98304; nt = 4; mode = 3; }
  int i = idx - base;
  int tile = i >> 9, e = i & 511;
  int lane = e >> 3, j = e & 7;
  int k0idx = tile / nt, tcol = tile - k0idx*nt;
  int n = tcol*16 + (lane & 15);
  int k = k0idx*32 + ((lane >> 4) << 3) + j;
  float val;
  if (mode == 0)      val = src[k*128 + n];
  else if (mode == 1) val = (k < 127) ? W0[k*128 + n] : 0.f;
  else if (mode == 2) val = (k == 127) ? 0.f
                           : ((k < 127) ? W2[k*128 + n] : W2[(k-1)*128 + n]);
  else                val = (k < 155) ? Wd[k*64 + n] : 0.f;
  wt[idx] = (half_t)val;
}

// ---------------------------------------------------------------------------
template<int NT>
__device__ inline void mfma_sw(const half_t* act, int astride, int rowbase,
                               const half_t* wlayer, int nt, int ktbase,
                               int tcolbase, int kchunk, v4f* acc, int lane){
  int m = lane & 15, quad = lane >> 4;
#pragma unroll
  for (int k0 = 0; k0 < kchunk; k0 += 32){
    v8h a = *(const v8h*)&act[(rowbase + m)*astride + k0 + quad*8];
    int krow = ktbase + (k0 >> 5);
#pragma unroll
    for (int t = 0; t < NT; t++){
      const half_t* bp = wlayer + ((size_t)((krow*nt + tcolbase + t) << 9) + (lane << 3));
      v8h b = *(const v8h*)bp;
      acc[t] = __builtin_amdgcn_mfma_f32_16x16x32_f16(a, b, acc[t], 0, 0, 0);
    }
  }
}

template<int NT>
__device__ inline void epilogue(v4f* acc, half_t* outb, int rowbase, int colbase,
                                const float* bias, bool relu, int lane){
  int n = lane & 15, quad = lane >> 4;
#pragma unroll
  for (int t = 0; t < NT; t++){
    int col = colbase + t*16 + n;
    float bv = bias[col];
#pragma unroll
    for (int r = 0; r < 4; r++){
      float v = acc[t][r] + bv;
      if (relu) v = fmaxf(v, 0.f);
      outb[(rowbase + quad*4 + r)*ASTRIDE + col] = (half_t)v;
    }
  }
}

// ---------------------------------------------------------------------------
// Fused kernel. Phase 1 (knn) is ARRAY-FREE: round-12's p[32] was compiled to
// scratch (5.5 GB HBM traffic — the whole regression). Keys are recomputed
// from lp in each pass instead (deterministic -> bit-identical):
//   pass 1: streaming lane-min; tau = max of 4 group-4th (n >= 16 guaranteed)
//   pass 2: recompute + ballot-compact into sl (<= SLCAP)
//   select: n<=64 net | n<=128 r[2] extraction | else exact increasing rescan
// Phase 2 (mlp): 8 waves x (16 rows x 32 cols), B-tiles from global (L2).
// ---------------------------------------------------------------------------
__global__ __launch_bounds__(512, 6) void fused_kernel(const int* indices,
    const float* qpts, const float4* cpos4, const float* codes,
    const float* xyzdir, const half_t* wt,
    const float* b0, const float* b1, const float* b2, const float* b3,
    const float* bfb, const float* bdb,
    const float* Wsb, const float* bsb, const float* Wrb, const float* brb,
    float* out){
  __shared__ __align__(16) char smem[48128];
  float4* lp   = (float4*)smem;                 // [0, 32768)    knn
  half_t* Pbuf = (half_t*)smem;                 // [0, 8704)     mlp (alias lp)
  half_t* Qbuf = (half_t*)(smem + 16384);       // [16384,25088) mlp (alias lp)
  int*    sl   = (int*)(smem + 32768);          // [32768,36864) knn
  half_t* Abuf = (half_t*)(smem + 36864);       // [36864,45568) both
  half_t* Dbuf = (half_t*)(smem + 45568);       // [45568,48128) both

  int tid = threadIdx.x;
  int lane = tid & 63, wave = tid >> 6;
  int l = lane & 15;
  int qbase = blockIdx.x * 32;
  const float* cc = codes + (size_t)indices[0] * N_C * CDIM;

  for (int c = tid; c < N_C; c += 512) lp[c] = cpos4[c];
  __syncthreads();

  // ---------------- Phase 1: exact 16-NN, 4 queries per wave ----------------
#pragma unroll 1
  for (int qi = 0; qi < 4; qi++){
    int lq = wave * 4 + qi;            // local query 0..31
    int q  = qbase + lq;
    float qx = qpts[q*3 + 0];
    float qy = qpts[q*3 + 1];
    float qz = qpts[q*3 + 2];
    float nqx = -2.0f*qx, nqy = -2.0f*qy, nqz = -2.0f*qz;

    // pass 1: streaming lane-min (no key array!)
    int lm = KINF;
#pragma unroll
    for (int j = 0; j < 32; j++){
      int c = j*64 + lane;
      float4 P = lp[c];
      float s = fmaf(P.x, nqx, fmaf(P.y, nqy, fmaf(P.z, nqz, P.w)));  // > 0
      lm = min(lm, (__float_as_int(s) & 0xFFFFF800) | c);
    }

    // sort lane-mins within 16-lane groups (10 stages)
    int v = lm;
#pragma unroll
    for (int k = 2; k <= 16; k <<= 1){
#pragma unroll
      for (int j = k >> 1; j > 0; j >>= 1){
        int o = __shfl_xor(v, j, 64);
        bool dirDesc = (l & k) != 0;
        bool lower   = (l & j) == 0;
        int mn = min(v, o), mx = max(v, o);
        v = (lower != dirDesc) ? mn : mx;
      }
    }
    int t0 = __shfl(v, 3, 64),  t1 = __shfl(v, 19, 64);
    int t2 = __shfl(v, 35, 64), t3 = __shfl(v, 51, 64);
    int tau = max(max(t0, t1), max(t2, t3));   // guarantees nsurv >= 16

    // pass 2: recompute keys, ballot-compact survivors into LDS
    int* slw = &sl[wave * SLCAP];
    int nsurv = 0;
#pragma unroll
    for (int j = 0; j < 32; j++){
      int c = j*64 + lane;
      float4 P = lp[c];
      float s = fmaf(P.x, nqx, fmaf(P.y, nqy, fmaf(P.z, nqz, P.w)));
      int key = (__float_as_int(s) & 0xFFFFF800) | c;
      bool take = (key <= tau);
      unsigned long long m = __ballot(take);
      if (m){
        if (take){
          int mb = __builtin_amdgcn_mbcnt_hi((unsigned)(m >> 32),
                   __builtin_amdgcn_mbcnt_lo((unsigned)m, 0));
          int pos = nsurv + mb;
          if (pos < SLCAP) slw[pos] = key;
        }
        nsurv += (int)__popcll(m);
      }
    }
    __builtin_amdgcn_wave_barrier();

    int keep = KINF;
    if (nsurv <= 64){
      // top-16-of-64 selection network -> lanes 0..15 hold the top-16 set
      int x = (lane < nsurv) ? slw[lane] : KINF;
#pragma unroll
      for (int k = 2; k <= 16; k <<= 1){
#pragma unroll
        for (int j = k >> 1; j > 0; j >>= 1){
          int o = __shfl_xor(x, j, 64);
          bool dirDesc = (l & k) != 0;
          bool lower   = (l & j) == 0;
          int mn = min(x, o), mx = max(x, o);
          x = (lower != dirDesc) ? mn : mx;
        }
      }
      x = min(x, __shfl_xor(x, 31, 64));
#pragma unroll
      for (int j = 8; j > 0; j >>= 1){
        int o = __shfl_xor(x, j, 64);
        bool lower = (l & j) == 0;
        int mn = min(x, o), mx = max(x, o);
        x = lower ? mn : mx;
      }
      x = min(x, __shfl_xor(x, 63, 64));
      keep = x;
    } else if (nsurv <= SLCAP){
      // r[2] extraction from the LDS survivor list
      int r0 = (lane < nsurv)      ? slw[lane]      : KINF;
      int r1 = (lane + 64 < nsurv) ? slw[lane + 64] : KINF;
#pragma unroll 1
      for (int rr = 0; rr < KNN_K; rr++){
        int gm = min(r0, r1);
#pragma unroll
        for (int off2 = 1; off2 < 64; off2 <<= 1)
          gm = min(gm, __shfl_xor(gm, off2, 64));
        if (lane == rr) keep = gm;
        r0 = (r0 == gm) ? KINF : r0;
        r1 = (r1 == gm) ? KINF : r1;
      }
    } else {
      // ultra-rare exact fallback: strictly-increasing extraction, keys
      // recomputed from lp each round (keys are unique -> exact)
      int last = -1;   // all keys > 0
#pragma unroll 1
      for (int rr = 0; rr < KNN_K; rr++){
        int cand = KINF;
#pragma unroll
        for (int j = 0; j < 32; j++){
          int c = j*64 + lane;
          float4 P = lp[c];
          float s = fmaf(P.x, nqx, fmaf(P.y, nqy, fmaf(P.z, nqz, P.w)));
          int key = (__float_as_int(s) & 0xFFFFF800) | c;
          if (key > last) cand = min(cand, key);
        }
#pragma unroll
        for (int off2 = 1; off2 < 64; off2 <<= 1)
          cand = min(cand, __shfl_xor(cand, off2, 64));
        if (lane == rr) keep = cand;
        last = cand;
      }
    }

    // exact d2 + inverse-d2 weights (lanes 0..15 meaningful)
    int ci = keep & 0x7FF;
    float4 P = lp[ci];
    float dx = qx - P.x, dy = qy - P.y, dz = qz - P.z;
    float d2 = fmaf(dz, dz, fmaf(dy, dy, dx*dx));
    float w = 1.0f / (d2 + 1e-16f);
    float wm = (lane < KNN_K) ? w : 0.0f;
#pragma unroll
    for (int off2 = 1; off2 < 64; off2 <<= 1) wm += __shfl_xor(wm, off2, 64);
    float wn = w / wm;

    float acc = 0.f;
#pragma unroll
    for (int i = 0; i < KNN_K; i++){
      int   cb = __shfl(ci, i, 64);
      float wb = __shfl(wn, i, 64);
      acc = fmaf(wb, cc[cb*CDIM + lane], acc);
    }
    int arow = lq * ASTRIDE;
    Abuf[arow + lane] = (half_t)acc;

    // activation staging: xyzdir -> Abuf cols 64..135 (with pads) and Dbuf
    float xv = (lane < 63) ? xyzdir[(size_t)q*90 + lane] : 0.f;
    Abuf[arow + 64 + lane] = (half_t)xv;
    if (lane < 8) Abuf[arow + 128 + lane] = (half_t)0.f;
    if (lane < 40){
      float dv = (lane < 27) ? xyzdir[(size_t)q*90 + 63 + lane] : 0.f;
      Dbuf[lq*DSTRIDE + lane] = (half_t)dv;
    }
  }
  __syncthreads();   // phase boundary: lp/sl dead; Pbuf/Qbuf may be written

  // ---------------- Phase 2: MFMA MLP, 8 waves x (16 rows x 32 cols) -------
  int rowbase  = (wave >> 2) * 16;
  int colq     = wave & 3;
  int colbase  = colq * 32;
  int tcolbase = colq * 2;
  v4f acc[2];

  const half_t* wt0 = wt;
  const half_t* wt1 = wt + 16384;
  const half_t* wt2 = wt + 32768;
  const half_t* wt3 = wt + 65536;
  const half_t* wtf = wt + 81920;
  const half_t* wtd = wt + 98304;

#define ZACC2() { for (int t_ = 0; t_ < 2; t_++) for (int e_ = 0; e_ < 4; e_++) acc[t_][e_] = 0.f; }

  // L0: A @ W0 -> P (relu)
  ZACC2();
  mfma_sw<2>(Abuf, ASTRIDE, rowbase, wt0, 8, 0, tcolbase, 128, acc, lane);
  epilogue<2>(acc, Pbuf, rowbase, colbase, b0, true, lane);
  __syncthreads();

  // L1: P @ W1 -> Q (relu)
  ZACC2();
  mfma_sw<2>(Pbuf, ASTRIDE, rowbase, wt1, 8, 0, tcolbase, 128, acc, lane);
  epilogue<2>(acc, Qbuf, rowbase, colbase, b1, true, lane);
  __syncthreads();

  // L2: [input_xyz | h1] @ W2 -> P (relu)   (K = 256)
  ZACC2();
  mfma_sw<2>(Abuf, ASTRIDE, rowbase, wt2, 8, 0, tcolbase, 128, acc, lane);
  mfma_sw<2>(Qbuf, ASTRIDE, rowbase, wt2, 8, 4, tcolbase, 128, acc, lane);
  epilogue<2>(acc, Pbuf, rowbase, colbase, b2, true, lane);
  __syncthreads();

  // L3: P @ W3 -> A (h3, kept for sigma; input_xyz dead)
  ZACC2();
  mfma_sw<2>(Pbuf, ASTRIDE, rowbase, wt3, 8, 0, tcolbase, 128, acc, lane);
  epilogue<2>(acc, Abuf, rowbase, colbase, b3, true, lane);
  __syncthreads();

  // Wf: A(h3) @ Wf -> P (no relu)
  ZACC2();
  mfma_sw<2>(Abuf, ASTRIDE, rowbase, wtf, 8, 0, tcolbase, 128, acc, lane);
  epilogue<2>(acc, Pbuf, rowbase, colbase, bfb, false, lane);
  __syncthreads();

  // Wd: [P(final) | D(dir)] @ Wd -> Q[:,0:64] (relu); nt=4, NT=1, tile = colq
  ZACC2();
  mfma_sw<1>(Pbuf, ASTRIDE, rowbase, wtd, 4, 0, colq, 128, acc, lane);
  mfma_sw<1>(Dbuf, DSTRIDE, rowbase, wtd, 4, 4, colq,  32, acc, lane);
  epilogue<1>(acc, Qbuf, rowbase, colq * 16, bdb, true, lane);
  __syncthreads();

  // Tail: sigma = h3(Abuf).Ws + bs ; rgb = d(Qbuf).Wr + br  (16 thr/query)
  {
    int q = tid >> 4, part = tid & 15;
    float s = 0.f;
#pragma unroll
    for (int k = 0; k < 8; k++){
      int kk = part*8 + k;
      s = fmaf((float)Abuf[q*ASTRIDE + kk], Wsb[kk], s);
    }
    s += __shfl_xor(s, 1, 64); s += __shfl_xor(s, 2, 64);
    s += __shfl_xor(s, 4, 64); s += __shfl_xor(s, 8, 64);

    float r3[3];
#pragma unroll
    for (int c2 = 0; c2 < 3; c2++){
      float rv = 0.f;
#pragma unroll
      for (int k = 0; k < 4; k++){
        int kk = part*4 + k;
        rv = fmaf((float)Qbuf[q*ASTRIDE + kk], Wrb[kk*3 + c2], rv);
      }
      rv += __shfl_xor(rv, 1, 64); rv += __shfl_xor(rv, 2, 64);
      rv += __shfl_xor(rv, 4, 64); rv += __shfl_xor(rv, 8, 64);
      r3[c2] = rv;
    }
    if (part == 0){
      size_t ob = ((size_t)(qbase + q)) * 4;
      out[ob + 0] = r3[0] + brb[0];
      out[ob + 1] = r3[1] + brb[1];
      out[ob + 2] = r3[2] + brb[2];
      out[ob + 3] = s + bsb[0];
    }
  }
}

// ---------------------------------------------------------------------------
extern "C" void kernel_launch(void* const* d_in, const int* in_sizes, int n_in,
                              void* d_out, int out_size, void* d_ws, size_t ws_size,
                              hipStream_t stream){
  (void)in_sizes; (void)n_in; (void)out_size; (void)ws_size;

  const int*   indices = (const int*)d_in[0];
  const float* qpts    = (const float*)d_in[1];
  const float* xyzdir  = (const float*)d_in[2];
  const float* cpos    = (const float*)d_in[3];
  const float* codes   = (const float*)d_in[4];
  const float* W0 = (const float*)d_in[5];
  const float* b0 = (const float*)d_in[6];
  const float* W1 = (const float*)d_in[7];
  const float* b1 = (const float*)d_in[8];
  const float* W2 = (const float*)d_in[9];
  const float* b2 = (const float*)d_in[10];
  const float* W3 = (const float*)d_in[11];
  const float* b3 = (const float*)d_in[12];
  const float* Wf = (const float*)d_in[13];
  const float* bf = (const float*)d_in[14];
  const float* Wd = (const float*)d_in[15];
  const float* bd = (const float*)d_in[16];
  const float* Ws = (const float*)d_in[17];
  const float* bs = (const float*)d_in[18];
  const float* Wr = (const float*)d_in[19];
  const float* br = (const float*)d_in[20];

  // ws layout: wt | cpos4
  half_t* wt    = (half_t*)d_ws;                          // 217,088 B
  float4* cpos4 = (float4*)((char*)d_ws + 217088);        //  32,768 B

  wtrans_kernel<<<(110592 + 255)/256, 256, 0, stream>>>(W0, W1, W2, W3, Wf, Wd,
                                                        indices, cpos, wt, cpos4);
  fused_kernel<<<N_Q/32, 512, 0, stream>>>(indices, qpts, cpos4, codes, xyzdir,
                                           wt, b0, b1, b2, b3, bf, bd,
                                           Ws, bs, Wr, br, (float*)d_out);
}

// Round 14
// 223.273 us; speedup vs baseline: 7.2188x; 1.6646x over previous
//
#include <hip/hip_runtime.h>

#define N_Q   65536
#define N_C   2048
#define KNN_K 16
#define CDIM  64
#define SLCAP 128
#define KINF  0x7FFFFFFF
#define WSZ   108544  // halves per weight image

typedef _Float16 half_t;
typedef float v4f __attribute__((ext_vector_type(4)));
typedef half_t v8h __attribute__((ext_vector_type(8)));

#define ASTRIDE 136   // 128 + 8 pad (halves); row = 272 B = 17*16 B
#define DSTRIDE 40    // 32 + 8 pad

// ---------------------------------------------------------------------------
// Kernel 0: weights -> fp16 MFMA-fragment-order tiles + cpos4 = (x,y,z,|c|^2+4)
// Tile (16 cols x 32 k) = 512 contiguous halves; element = lane*8+j,
// lane = (n&15)+16*quad, k = k0*32 + quad*8 + j. Tiles ordered [k0][tcol].
// ---------------------------------------------------------------------------
__global__ void wtrans_kernel(const float* W0, const float* W1, const float* W2,
                              const float* W3, const float* Wf, const float* Wd,
                              const int* indices, const float* cpos,
                              half_t* wt, float4* cpos4){
  int idx = blockIdx.x * 256 + threadIdx.x;
  if (idx >= 110592) return;
  if (idx >= WSZ){
    int i = idx - WSZ;
    const float* cp = cpos + (size_t)indices[0] * N_C * 3;
    float x = cp[i*3 + 0], y = cp[i*3 + 1], z = cp[i*3 + 2];
    cpos4[i] = make_float4(x, y, z, fmaf(x, x, fmaf(y, y, fmaf(z, z, 4.0f))));
    return;
  }
  int base, nt, mode;            // mode: 0 plain(src), 1 W0, 2 W2, 3 Wd
  const float* src = W1;
  if (idx < 16384){ base = 0; nt = 8; mode = 1; }
  else if (idx < 32768){ base = 16384; nt = 8; mode = 0; src = W1; }
  else if (idx < 65536){ base = 32768; nt = 8; mode = 2; }
  else if (idx < 81920){ base = 65536; nt = 8; mode = 0; src = W3; }
  else if (idx < 98304){ base = 81920; nt = 8; mode = 0; src = Wf; }
  else { base = 98304; nt = 4; mode = 3; }
  int i = idx - base;
  int tile = i >> 9, e = i & 511;
  int lane = e >> 3, j = e & 7;
  int k0idx = tile / nt, tcol = tile - k0idx*nt;
  int n = tcol*16 + (lane & 15);
  int k = k0idx*32 + ((lane >> 4) << 3) + j;
  float val;
  if (mode == 0)      val = src[k*128 + n];
  else if (mode == 1) val = (k < 127) ? W0[k*128 + n] : 0.f;
  else if (mode == 2) val = (k == 127) ? 0.f
                           : ((k < 127) ? W2[k*128 + n] : W2[(k-1)*128 + n]);
  else                val = (k < 155) ? Wd[k*64 + n] : 0.f;
  wt[idx] = (half_t)val;
}

// ---------------------------------------------------------------------------
// Kernel 1: exact 16-NN + activation staging (round-11 verbatim: 102 us,
// 32 VGPR, no scratch). One wave per query, 8 queries/block.
// ---------------------------------------------------------------------------
__global__ __launch_bounds__(512, 8) void knn_kernel(const int* indices,
    const float* qpts, const float4* cpos4, const float* codes,
    const float* xyzdir, half_t* Ain, half_t* Din){
  __shared__ float4 lp[N_C];        // 32 KB
  __shared__ int    sl[8*SLCAP];    // 4 KB
  int tid = threadIdx.x;
  int lane = tid & 63, wave = tid >> 6;
  int l = lane & 15;                // lane within 16-group
  const float* cc = codes + (size_t)indices[0] * N_C * CDIM;

  for (int c = tid; c < N_C; c += 512) lp[c] = cpos4[c];
  __syncthreads();

  int q = blockIdx.x * 8 + wave;
  float qx = qpts[q*3 + 0];
  float qy = qpts[q*3 + 1];
  float qz = qpts[q*3 + 2];
  float nqx = -2.0f*qx, nqy = -2.0f*qy, nqz = -2.0f*qz;

  int p[32];
#pragma unroll
  for (int j = 0; j < 32; j++){
    int c = j*64 + lane;
    float4 P = lp[c];
    float s = fmaf(P.x, nqx, fmaf(P.y, nqy, fmaf(P.z, nqz, P.w)));  // > 0
    p[j] = (__float_as_int(s) & 0xFFFFF800) | c;
  }

  // lane-local min
  int lm = p[0];
#pragma unroll
  for (int j = 1; j < 32; j++) lm = min(lm, p[j]);

  // sort lane-mins ascending WITHIN each 16-lane group (10 stages)
  int v = lm;
#pragma unroll
  for (int k = 2; k <= 16; k <<= 1){
#pragma unroll
    for (int j = k >> 1; j > 0; j >>= 1){
      int o = __shfl_xor(v, j, 64);
      bool dirDesc = (l & k) != 0;
      bool lower   = (l & j) == 0;
      int mn = min(v, o), mx = max(v, o);
      v = (lower != dirDesc) ? mn : mx;
    }
  }
  // tau = max over groups of group's 4th-smallest -> n >= 16 guaranteed
  int t0 = __shfl(v, 3, 64),  t1 = __shfl(v, 19, 64);
  int t2 = __shfl(v, 35, 64), t3 = __shfl(v, 51, 64);
  int tau = max(max(t0, t1), max(t2, t3));

  // ballot-compaction: scalar running n, per-lane position via mbcnt
  int* slw = &sl[wave * SLCAP];
  int n = 0;
#pragma unroll
  for (int j = 0; j < 32; j++){
    bool c = (p[j] <= tau);
    unsigned long long m = __ballot(c);
    if (m){
      if (n <= 64){
        if (c){
          int mb = __builtin_amdgcn_mbcnt_hi((unsigned)(m >> 32),
                   __builtin_amdgcn_mbcnt_lo((unsigned)m, 0));
          slw[n + mb] = p[j];
        }
      }
      n += (int)__popcll(m);
    }
  }
  __builtin_amdgcn_wave_barrier();

  int keep;
  if (n >= KNN_K && n <= 64){
    // top-16-of-64 selection network -> lanes 0..15 hold the top-16 set
    int x = (lane < n) ? slw[lane] : KINF;
#pragma unroll
    for (int k = 2; k <= 16; k <<= 1){
#pragma unroll
      for (int j = k >> 1; j > 0; j >>= 1){
        int o = __shfl_xor(x, j, 64);
        bool dirDesc = (l & k) != 0;
        bool lower   = (l & j) == 0;
        int mn = min(x, o), mx = max(x, o);
        x = (lower != dirDesc) ? mn : mx;
      }
    }
    x = min(x, __shfl_xor(x, 31, 64));
#pragma unroll
    for (int j = 8; j > 0; j >>= 1){
      int o = __shfl_xor(x, j, 64);
      bool lower = (l & j) == 0;
      int mn = min(x, o), mx = max(x, o);
      x = lower ? mn : mx;
    }
    x = min(x, __shfl_xor(x, 63, 64));
    keep = x;
  } else {
    // exact fallback: full rescan extraction over p[32] (rare)
    keep = KINF;
#pragma unroll 1
    for (int rr = 0; rr < KNN_K; rr++){
      int lmf = p[0];
#pragma unroll
      for (int j = 1; j < 32; j++) lmf = min(lmf, p[j]);
      int gm = lmf;
#pragma unroll
      for (int off2 = 1; off2 < 64; off2 <<= 1)
        gm = min(gm, __shfl_xor(gm, off2, 64));
      if (lane == rr) keep = gm;
#pragma unroll
      for (int j = 0; j < 32; j++) p[j] = (p[j] == gm) ? KINF : p[j];
    }
  }

  // exact d2 + inverse-d2 weights (lanes 0..15 meaningful)
  int ci = keep & 0x7FF;
  float4 P = lp[ci];
  float dx = qx - P.x, dy = qy - P.y, dz = qz - P.z;
  float d2 = fmaf(dz, dz, fmaf(dy, dy, dx*dx));
  float w = 1.0f / (d2 + 1e-16f);
  float wm = (lane < KNN_K) ? w : 0.0f;
#pragma unroll
  for (int off2 = 1; off2 < 64; off2 <<= 1) wm += __shfl_xor(wm, off2, 64);
  float wn = w / wm;

  float acc = 0.f;
#pragma unroll
  for (int i = 0; i < KNN_K; i++){
    int   cb = __shfl(ci, i, 64);
    float wb = __shfl(wn, i, 64);
    acc = fmaf(wb, cc[cb*CDIM + lane], acc);
  }
  size_t arow = (size_t)q * ASTRIDE;
  Ain[arow + lane] = (half_t)acc;

  // folded prep: xyzdir -> Ain cols 64..135 (incl. zero pads) and Din
  float xv = (lane < 63) ? xyzdir[(size_t)q*90 + lane] : 0.f;
  Ain[arow + 64 + lane] = (half_t)xv;
  if (lane < 8) Ain[arow + 128 + lane] = (half_t)0.f;
  if (lane < 40){
    float dv = (lane < 27) ? xyzdir[(size_t)q*90 + 63 + lane] : 0.f;
    Din[(size_t)q*DSTRIDE + lane] = (half_t)dv;
  }
}

// ---------------------------------------------------------------------------
// Kernel 2: fused MFMA MLP. 64 queries/block, 512 threads (8 waves).
// Wave = 32 rows x 32 cols: each 1 KB B-tile load now feeds TWO MFMAs
// (2 A-fragments), and blocks halve -> half the L2 weight traffic.
// rowg = wave>>2 (rows rowg*32..+32), colq = wave&3 (cols colq*32..+32).
// ---------------------------------------------------------------------------
template<int NT>
__device__ inline void mfma64(const half_t* act, int astride, int rowbase,
                              const half_t* wlayer, int nt, int ktbase,
                              int tcolbase, int kchunk, v4f acc[2][NT], int lane){
  int m = lane & 15, quad = lane >> 4;
#pragma unroll
  for (int k0 = 0; k0 < kchunk; k0 += 32){
    v8h a0 = *(const v8h*)&act[(rowbase + m)*astride + k0 + quad*8];
    v8h a1 = *(const v8h*)&act[(rowbase + 16 + m)*astride + k0 + quad*8];
    int krow = ktbase + (k0 >> 5);
#pragma unroll
    for (int t = 0; t < NT; t++){
      const half_t* bp = wlayer + ((size_t)((krow*nt + tcolbase + t) << 9) + (lane << 3));
      v8h b = *(const v8h*)bp;
      acc[0][t] = __builtin_amdgcn_mfma_f32_16x16x32_f16(a0, b, acc[0][t], 0, 0, 0);
      acc[1][t] = __builtin_amdgcn_mfma_f32_16x16x32_f16(a1, b, acc[1][t], 0, 0, 0);
    }
  }
}

template<int NT>
__device__ inline void epilogue64(v4f acc[2][NT], half_t* outb, int rowbase,
                                  int colbase, const float* bias, bool relu,
                                  int lane){
  int n = lane & 15, quad = lane >> 4;
#pragma unroll
  for (int t = 0; t < NT; t++){
    int col = colbase + t*16 + n;
    float bv = bias[col];
#pragma unroll
    for (int g = 0; g < 2; g++){
#pragma unroll
      for (int r = 0; r < 4; r++){
        float v = acc[g][t][r] + bv;
        if (relu) v = fmaxf(v, 0.f);
        outb[(rowbase + g*16 + quad*4 + r)*ASTRIDE + col] = (half_t)v;
      }
    }
  }
}

__global__ __launch_bounds__(512, 4) void mlp_mfma(
    const half_t* Ain, const half_t* Din, const half_t* wt,
    const float* b0, const float* b1, const float* b2, const float* b3,
    const float* bfb, const float* bdb,
    const float* Wsb, const float* bsb, const float* Wrb, const float* brb,
    float* out){
  __shared__ __align__(16) half_t Abuf[64*ASTRIDE];
  __shared__ __align__(16) half_t Pbuf[64*ASTRIDE];
  __shared__ __align__(16) half_t Qbuf[64*ASTRIDE];
  __shared__ __align__(16) half_t Dbuf[64*DSTRIDE];

  int tid = threadIdx.x, lane = tid & 63, wave = tid >> 6;
  int qbase = blockIdx.x * 64;

  for (int i = tid; i < 64*17; i += 512){
    int r = i / 17, c8 = i - r*17;
    *(uint4*)&Abuf[r*ASTRIDE + (c8 << 3)] =
        *(const uint4*)&Ain[(size_t)(qbase + r)*ASTRIDE + (c8 << 3)];
  }
  for (int i = tid; i < 64*5; i += 512){
    int r = i / 5, c8 = i - r*5;
    *(uint4*)&Dbuf[r*DSTRIDE + (c8 << 3)] =
        *(const uint4*)&Din[(size_t)(qbase + r)*DSTRIDE + (c8 << 3)];
  }
  __syncthreads();

  int rowbase  = (wave >> 2) * 32;
  int colq     = wave & 3;
  int colbase  = colq * 32;
  int tcolbase = colq * 2;
  v4f acc[2][2];
  v4f accd[2][1];

  const half_t* wt0 = wt;
  const half_t* wt1 = wt + 16384;
  const half_t* wt2 = wt + 32768;
  const half_t* wt3 = wt + 65536;
  const half_t* wtf = wt + 81920;
  const half_t* wtd = wt + 98304;

#define ZACC22() { for (int g_ = 0; g_ < 2; g_++) for (int t_ = 0; t_ < 2; t_++) \
                   for (int e_ = 0; e_ < 4; e_++) acc[g_][t_][e_] = 0.f; }

  // L0: A @ W0 -> P (relu)
  ZACC22();
  mfma64<2>(Abuf, ASTRIDE, rowbase, wt0, 8, 0, tcolbase, 128, acc, lane);
  epilogue64<2>(acc, Pbuf, rowbase, colbase, b0, true, lane);
  __syncthreads();

  // L1: P @ W1 -> Q (relu)
  ZACC22();
  mfma64<2>(Pbuf, ASTRIDE, rowbase, wt1, 8, 0, tcolbase, 128, acc, lane);
  epilogue64<2>(acc, Qbuf, rowbase, colbase, b1, true, lane);
  __syncthreads();

  // L2: [input_xyz | h1] @ W2 -> P (relu)   (K = 256)
  ZACC22();
  mfma64<2>(Abuf, ASTRIDE, rowbase, wt2, 8, 0, tcolbase, 128, acc, lane);
  mfma64<2>(Qbuf, ASTRIDE, rowbase, wt2, 8, 4, tcolbase, 128, acc, lane);
  epilogue64<2>(acc, Pbuf, rowbase, colbase, b2, true, lane);
  __syncthreads();

  // L3: P @ W3 -> A (h3, kept for sigma; input_xyz dead)
  ZACC22();
  mfma64<2>(Pbuf, ASTRIDE, rowbase, wt3, 8, 0, tcolbase, 128, acc, lane);
  epilogue64<2>(acc, Abuf, rowbase, colbase, b3, true, lane);
  __syncthreads();

  // Wf: A(h3) @ Wf -> P (no relu)
  ZACC22();
  mfma64<2>(Abuf, ASTRIDE, rowbase, wtf, 8, 0, tcolbase, 128, acc, lane);
  epilogue64<2>(acc, Pbuf, rowbase, colbase, bfb, false, lane);
  __syncthreads();

  // Wd: [P(final) | D(dir)] @ Wd -> Q[:,0:64] (relu); nt=4, NT=1, tile = colq
#pragma unroll
  for (int g_ = 0; g_ < 2; g_++)
#pragma unroll
    for (int e_ = 0; e_ < 4; e_++) accd[g_][0][e_] = 0.f;
  mfma64<1>(Pbuf, ASTRIDE, rowbase, wtd, 4, 0, colq, 128, accd, lane);
  mfma64<1>(Dbuf, DSTRIDE, rowbase, wtd, 4, 4, colq,  32, accd, lane);
  epilogue64<1>(accd, Qbuf, rowbase, colq * 16, bdb, true, lane);
  __syncthreads();

  // Tail: sigma = h3(Abuf).Ws + bs ; rgb = d(Qbuf).Wr + br  (8 thr/query)
  {
    int q = tid >> 3, part = tid & 7;
    float s = 0.f;
#pragma unroll
    for (int k = 0; k < 16; k++){
      int kk = part*16 + k;
      s = fmaf((float)Abuf[q*ASTRIDE + kk], Wsb[kk], s);
    }
    s += __shfl_xor(s, 1, 64); s += __shfl_xor(s, 2, 64); s += __shfl_xor(s, 4, 64);

    float r3[3];
#pragma unroll
    for (int c2 = 0; c2 < 3; c2++){
      float rv = 0.f;
#pragma unroll
      for (int k = 0; k < 8; k++){
        int kk = part*8 + k;
        rv = fmaf((float)Qbuf[q*ASTRIDE + kk], Wrb[kk*3 + c2], rv);
      }
      rv += __shfl_xor(rv, 1, 64); rv += __shfl_xor(rv, 2, 64); rv += __shfl_xor(rv, 4, 64);
      r3[c2] = rv;
    }
    if (part == 0){
      size_t ob = ((size_t)(qbase + q)) * 4;
      out[ob + 0] = r3[0] + brb[0];
      out[ob + 1] = r3[1] + brb[1];
      out[ob + 2] = r3[2] + brb[2];
      out[ob + 3] = s + bsb[0];
    }
  }
}

// ---------------------------------------------------------------------------
extern "C" void kernel_launch(void* const* d_in, const int* in_sizes, int n_in,
                              void* d_out, int out_size, void* d_ws, size_t ws_size,
                              hipStream_t stream){
  (void)in_sizes; (void)n_in; (void)out_size; (void)ws_size;

  const int*   indices = (const int*)d_in[0];
  const float* qpts    = (const float*)d_in[1];
  const float* xyzdir  = (const float*)d_in[2];
  const float* cpos    = (const float*)d_in[3];
  const float* codes   = (const float*)d_in[4];
  const float* W0 = (const float*)d_in[5];
  const float* b0 = (const float*)d_in[6];
  const float* W1 = (const float*)d_in[7];
  const float* b1 = (const float*)d_in[8];
  const float* W2 = (const float*)d_in[9];
  const float* b2 = (const float*)d_in[10];
  const float* W3 = (const float*)d_in[11];
  const float* b3 = (const float*)d_in[12];
  const float* Wf = (const float*)d_in[13];
  const float* bf = (const float*)d_in[14];
  const float* Wd = (const float*)d_in[15];
  const float* bd = (const float*)d_in[16];
  const float* Ws = (const float*)d_in[17];
  const float* bs = (const float*)d_in[18];
  const float* Wr = (const float*)d_in[19];
  const float* br = (const float*)d_in[20];

  // ws layout (16-B aligned): Ain | Din | wt | cpos4
  half_t* Ain   = (half_t*)d_ws;                                   // 17,825,792 B
  half_t* Din   = (half_t*)((char*)d_ws + 17825792);               //  5,242,880 B
  half_t* wt    = (half_t*)((char*)d_ws + 17825792 + 5242880);     //    217,088 B
  float4* cpos4 = (float4*)((char*)d_ws + 17825792 + 5242880 + 217088);

  wtrans_kernel<<<(110592 + 255)/256, 256, 0, stream>>>(W0, W1, W2, W3, Wf, Wd,
                                                        indices, cpos, wt, cpos4);
  knn_kernel<<<N_Q/8, 512, 0, stream>>>(indices, qpts, cpos4, codes, xyzdir,
                                        Ain, Din);
  mlp_mfma<<<N_Q/64, 512, 0, stream>>>(Ain, Din, wt,
                                       b0, b1, b2, b3, bf, bd, Ws, bs, Wr, br,
                                       (float*)d_out);
}

// Round 15
// 222.768 us; speedup vs baseline: 7.2352x; 1.0023x over previous
//
#include <hip/hip_runtime.h>

#define N_Q   65536
#define N_C   2048
#define KNN_K 16
#define CDIM  64
#define SLCAP 128
#define KINF  0x7FFFFFFF
#define WSZ   108544  // halves per weight image

typedef _Float16 half_t;
typedef float v4f __attribute__((ext_vector_type(4)));
typedef half_t v8h __attribute__((ext_vector_type(8)));

#define ASTRIDE 136   // 128 + 8 pad (halves); row = 272 B = 17*16 B
#define DSTRIDE 40    // 32 + 8 pad

// ---------------------------------------------------------------------------
// Kernel 0: weights -> fp16 MFMA-fragment-order tiles + cpos4 = (x,y,z,|c|^2+4)
// (unchanged from round 14)
// ---------------------------------------------------------------------------
__global__ void wtrans_kernel(const float* W0, const float* W1, const float* W2,
                              const float* W3, const float* Wf, const float* Wd,
                              const int* indices, const float* cpos,
                              half_t* wt, float4* cpos4){
  int idx = blockIdx.x * 256 + threadIdx.x;
  if (idx >= 110592) return;
  if (idx >= WSZ){
    int i = idx - WSZ;
    const float* cp = cpos + (size_t)indices[0] * N_C * 3;
    float x = cp[i*3 + 0], y = cp[i*3 + 1], z = cp[i*3 + 2];
    cpos4[i] = make_float4(x, y, z, fmaf(x, x, fmaf(y, y, fmaf(z, z, 4.0f))));
    return;
  }
  int base, nt, mode;            // mode: 0 plain(src), 1 W0, 2 W2, 3 Wd
  const float* src = W1;
  if (idx < 16384){ base = 0; nt = 8; mode = 1; }
  else if (idx < 32768){ base = 16384; nt = 8; mode = 0; src = W1; }
  else if (idx < 65536){ base = 32768; nt = 8; mode = 2; }
  else if (idx < 81920){ base = 65536; nt = 8; mode = 0; src = W3; }
  else if (idx < 98304){ base = 81920; nt = 8; mode = 0; src = Wf; }
  else { base = 98304; nt = 4; mode = 3; }
  int i = idx - base;
  int tile = i >> 9, e = i & 511;
  int lane = e >> 3, j = e & 7;
  int k0idx = tile / nt, tcol = tile - k0idx*nt;
  int n = tcol*16 + (lane & 15);
  int k = k0idx*32 + ((lane >> 4) << 3) + j;
  float val;
  if (mode == 0)      val = src[k*128 + n];
  else if (mode == 1) val = (k < 127) ? W0[k*128 + n] : 0.f;
  else if (mode == 2) val = (k == 127) ? 0.f
                           : ((k < 127) ? W2[k*128 + n] : W2[(k-1)*128 + n]);
  else                val = (k < 155) ? Wd[k*64 + n] : 0.f;
  wt[idx] = (half_t)val;
}

// ---------------------------------------------------------------------------
// Kernel 1: exact 16-NN + activation staging (round-11/14 verbatim, frozen).
// ---------------------------------------------------------------------------
__global__ __launch_bounds__(512, 8) void knn_kernel(const int* indices,
    const float* qpts, const float4* cpos4, const float* codes,
    const float* xyzdir, half_t* Ain, half_t* Din){
  __shared__ float4 lp[N_C];        // 32 KB
  __shared__ int    sl[8*SLCAP];    // 4 KB
  int tid = threadIdx.x;
  int lane = tid & 63, wave = tid >> 6;
  int l = lane & 15;                // lane within 16-group
  const float* cc = codes + (size_t)indices[0] * N_C * CDIM;

  for (int c = tid; c < N_C; c += 512) lp[c] = cpos4[c];
  __syncthreads();

  int q = blockIdx.x * 8 + wave;
  float qx = qpts[q*3 + 0];
  float qy = qpts[q*3 + 1];
  float qz = qpts[q*3 + 2];
  float nqx = -2.0f*qx, nqy = -2.0f*qy, nqz = -2.0f*qz;

  int p[32];
#pragma unroll
  for (int j = 0; j < 32; j++){
    int c = j*64 + lane;
    float4 P = lp[c];
    float s = fmaf(P.x, nqx, fmaf(P.y, nqy, fmaf(P.z, nqz, P.w)));  // > 0
    p[j] = (__float_as_int(s) & 0xFFFFF800) | c;
  }

  int lm = p[0];
#pragma unroll
  for (int j = 1; j < 32; j++) lm = min(lm, p[j]);

  int v = lm;
#pragma unroll
  for (int k = 2; k <= 16; k <<= 1){
#pragma unroll
    for (int j = k >> 1; j > 0; j >>= 1){
      int o = __shfl_xor(v, j, 64);
      bool dirDesc = (l & k) != 0;
      bool lower   = (l & j) == 0;
      int mn = min(v, o), mx = max(v, o);
      v = (lower != dirDesc) ? mn : mx;
    }
  }
  int t0 = __shfl(v, 3, 64),  t1 = __shfl(v, 19, 64);
  int t2 = __shfl(v, 35, 64), t3 = __shfl(v, 51, 64);
  int tau = max(max(t0, t1), max(t2, t3));

  int* slw = &sl[wave * SLCAP];
  int n = 0;
#pragma unroll
  for (int j = 0; j < 32; j++){
    bool c = (p[j] <= tau);
    unsigned long long m = __ballot(c);
    if (m){
      if (n <= 64){
        if (c){
          int mb = __builtin_amdgcn_mbcnt_hi((unsigned)(m >> 32),
                   __builtin_amdgcn_mbcnt_lo((unsigned)m, 0));
          slw[n + mb] = p[j];
        }
      }
      n += (int)__popcll(m);
    }
  }
  __builtin_amdgcn_wave_barrier();

  int keep;
  if (n >= KNN_K && n <= 64){
    int x = (lane < n) ? slw[lane] : KINF;
#pragma unroll
    for (int k = 2; k <= 16; k <<= 1){
#pragma unroll
      for (int j = k >> 1; j > 0; j >>= 1){
        int o = __shfl_xor(x, j, 64);
        bool dirDesc = (l & k) != 0;
        bool lower   = (l & j) == 0;
        int mn = min(x, o), mx = max(x, o);
        x = (lower != dirDesc) ? mn : mx;
      }
    }
    x = min(x, __shfl_xor(x, 31, 64));
#pragma unroll
    for (int j = 8; j > 0; j >>= 1){
      int o = __shfl_xor(x, j, 64);
      bool lower = (l & j) == 0;
      int mn = min(x, o), mx = max(x, o);
      x = lower ? mn : mx;
    }
    x = min(x, __shfl_xor(x, 63, 64));
    keep = x;
  } else {
    keep = KINF;
#pragma unroll 1
    for (int rr = 0; rr < KNN_K; rr++){
      int lmf = p[0];
#pragma unroll
      for (int j = 1; j < 32; j++) lmf = min(lmf, p[j]);
      int gm = lmf;
#pragma unroll
      for (int off2 = 1; off2 < 64; off2 <<= 1)
        gm = min(gm, __shfl_xor(gm, off2, 64));
      if (lane == rr) keep = gm;
#pragma unroll
      for (int j = 0; j < 32; j++) p[j] = (p[j] == gm) ? KINF : p[j];
    }
  }

  int ci = keep & 0x7FF;
  float4 P = lp[ci];
  float dx = qx - P.x, dy = qy - P.y, dz = qz - P.z;
  float d2 = fmaf(dz, dz, fmaf(dy, dy, dx*dx));
  float w = 1.0f / (d2 + 1e-16f);
  float wm = (lane < KNN_K) ? w : 0.0f;
#pragma unroll
  for (int off2 = 1; off2 < 64; off2 <<= 1) wm += __shfl_xor(wm, off2, 64);
  float wn = w / wm;

  float acc = 0.f;
#pragma unroll
  for (int i = 0; i < KNN_K; i++){
    int   cb = __shfl(ci, i, 64);
    float wb = __shfl(wn, i, 64);
    acc = fmaf(wb, cc[cb*CDIM + lane], acc);
  }
  size_t arow = (size_t)q * ASTRIDE;
  Ain[arow + lane] = (half_t)acc;

  float xv = (lane < 63) ? xyzdir[(size_t)q*90 + lane] : 0.f;
  Ain[arow + 64 + lane] = (half_t)xv;
  if (lane < 8) Ain[arow + 128 + lane] = (half_t)0.f;
  if (lane < 40){
    float dv = (lane < 27) ? xyzdir[(size_t)q*90 + 63 + lane] : 0.f;
    Din[(size_t)q*DSTRIDE + lane] = (half_t)dv;
  }
}

// ---------------------------------------------------------------------------
// Kernel 2: fused MFMA MLP, 64 queries/block. ROUND-15 CHANGE: explicit
// software pipelining — ALL of a layer's B-tiles are preloaded into a
// register array (NCH*NT x v8h = up to 32 VGPRs) BEFORE the MFMA chain, so
// MFMAs wait on partial vmcnt while later loads are still in flight.
// (R7 evidence: 48-VGPR allocation kept one b in flight -> per-MFMA vmcnt
// serialization -> MfmaUtil 4.6%, 85% idle.)
// ---------------------------------------------------------------------------
template<int NCH, int NT>
__device__ inline void mfma_pl(const half_t* act, int astride, int rowbase,
                               const half_t* wlayer, int nt, int ktbase,
                               int tcolbase, v4f acc[2][NT], int lane){
  v8h breg[NCH*NT];
#pragma unroll
  for (int c = 0; c < NCH; c++){
#pragma unroll
    for (int t = 0; t < NT; t++){
      const half_t* bp = wlayer +
          ((size_t)(((ktbase + c)*nt + tcolbase + t) << 9) + (lane << 3));
      breg[c*NT + t] = *(const v8h*)bp;
    }
  }
  int m = lane & 15, quad = lane >> 4;
#pragma unroll
  for (int c = 0; c < NCH; c++){
    v8h a0 = *(const v8h*)&act[(rowbase + m)*astride + c*32 + quad*8];
    v8h a1 = *(const v8h*)&act[(rowbase + 16 + m)*astride + c*32 + quad*8];
#pragma unroll
    for (int t = 0; t < NT; t++){
      acc[0][t] = __builtin_amdgcn_mfma_f32_16x16x32_f16(a0, breg[c*NT + t], acc[0][t], 0, 0, 0);
      acc[1][t] = __builtin_amdgcn_mfma_f32_16x16x32_f16(a1, breg[c*NT + t], acc[1][t], 0, 0, 0);
    }
  }
}

template<int NT>
__device__ inline void epilogue64(v4f acc[2][NT], half_t* outb, int rowbase,
                                  int colbase, const float* bias, bool relu,
                                  int lane){
  int n = lane & 15, quad = lane >> 4;
#pragma unroll
  for (int t = 0; t < NT; t++){
    int col = colbase + t*16 + n;
    float bv = bias[col];
#pragma unroll
    for (int g = 0; g < 2; g++){
#pragma unroll
      for (int r = 0; r < 4; r++){
        float v = acc[g][t][r] + bv;
        if (relu) v = fmaxf(v, 0.f);
        outb[(rowbase + g*16 + quad*4 + r)*ASTRIDE + col] = (half_t)v;
      }
    }
  }
}

__global__ __launch_bounds__(512, 4) void mlp_mfma(
    const half_t* Ain, const half_t* Din, const half_t* wt,
    const float* b0, const float* b1, const float* b2, const float* b3,
    const float* bfb, const float* bdb,
    const float* Wsb, const float* bsb, const float* Wrb, const float* brb,
    float* out){
  __shared__ __align__(16) half_t Abuf[64*ASTRIDE];
  __shared__ __align__(16) half_t Pbuf[64*ASTRIDE];
  __shared__ __align__(16) half_t Qbuf[64*ASTRIDE];
  __shared__ __align__(16) half_t Dbuf[64*DSTRIDE];

  int tid = threadIdx.x, lane = tid & 63, wave = tid >> 6;
  int qbase = blockIdx.x * 64;

  for (int i = tid; i < 64*17; i += 512){
    int r = i / 17, c8 = i - r*17;
    *(uint4*)&Abuf[r*ASTRIDE + (c8 << 3)] =
        *(const uint4*)&Ain[(size_t)(qbase + r)*ASTRIDE + (c8 << 3)];
  }
  for (int i = tid; i < 64*5; i += 512){
    int r = i / 5, c8 = i - r*5;
    *(uint4*)&Dbuf[r*DSTRIDE + (c8 << 3)] =
        *(const uint4*)&Din[(size_t)(qbase + r)*DSTRIDE + (c8 << 3)];
  }
  __syncthreads();

  int rowbase  = (wave >> 2) * 32;
  int colq     = wave & 3;
  int colbase  = colq * 32;
  int tcolbase = colq * 2;
  v4f acc[2][2];
  v4f accd[2][1];

  const half_t* wt0 = wt;
  const half_t* wt1 = wt + 16384;
  const half_t* wt2 = wt + 32768;
  const half_t* wt3 = wt + 65536;
  const half_t* wtf = wt + 81920;
  const half_t* wtd = wt + 98304;

#define ZACC22() { for (int g_ = 0; g_ < 2; g_++) for (int t_ = 0; t_ < 2; t_++) \
                   for (int e_ = 0; e_ < 4; e_++) acc[g_][t_][e_] = 0.f; }

  // L0: A @ W0 -> P (relu)
  ZACC22();
  mfma_pl<4,2>(Abuf, ASTRIDE, rowbase, wt0, 8, 0, tcolbase, acc, lane);
  epilogue64<2>(acc, Pbuf, rowbase, colbase, b0, true, lane);
  __syncthreads();

  // L1: P @ W1 -> Q (relu)
  ZACC22();
  mfma_pl<4,2>(Pbuf, ASTRIDE, rowbase, wt1, 8, 0, tcolbase, acc, lane);
  epilogue64<2>(acc, Qbuf, rowbase, colbase, b1, true, lane);
  __syncthreads();

  // L2: [input_xyz | h1] @ W2 -> P (relu)   (K = 256)
  ZACC22();
  mfma_pl<4,2>(Abuf, ASTRIDE, rowbase, wt2, 8, 0, tcolbase, acc, lane);
  mfma_pl<4,2>(Qbuf, ASTRIDE, rowbase, wt2, 8, 4, tcolbase, acc, lane);
  epilogue64<2>(acc, Pbuf, rowbase, colbase, b2, true, lane);
  __syncthreads();

  // L3: P @ W3 -> A (h3, kept for sigma; input_xyz dead)
  ZACC22();
  mfma_pl<4,2>(Pbuf, ASTRIDE, rowbase, wt3, 8, 0, tcolbase, acc, lane);
  epilogue64<2>(acc, Abuf, rowbase, colbase, b3, true, lane);
  __syncthreads();

  // Wf: A(h3) @ Wf -> P (no relu)
  ZACC22();
  mfma_pl<4,2>(Abuf, ASTRIDE, rowbase, wtf, 8, 0, tcolbase, acc, lane);
  epilogue64<2>(acc, Pbuf, rowbase, colbase, bfb, false, lane);
  __syncthreads();

  // Wd: [P(final) | D(dir)] @ Wd -> Q[:,0:64] (relu); nt=4, NT=1, tile = colq
#pragma unroll
  for (int g_ = 0; g_ < 2; g_++)
#pragma unroll
    for (int e_ = 0; e_ < 4; e_++) accd[g_][0][e_] = 0.f;
  mfma_pl<4,1>(Pbuf, ASTRIDE, rowbase, wtd, 4, 0, colq, accd, lane);
  mfma_pl<1,1>(Dbuf, DSTRIDE, rowbase, wtd, 4, 4, colq, accd, lane);
  epilogue64<1>(accd, Qbuf, rowbase, colq * 16, bdb, true, lane);
  __syncthreads();

  // Tail: sigma = h3(Abuf).Ws + bs ; rgb = d(Qbuf).Wr + br  (8 thr/query)
  {
    int q = tid >> 3, part = tid & 7;
    float s = 0.f;
#pragma unroll
    for (int k = 0; k < 16; k++){
      int kk = part*16 + k;
      s = fmaf((float)Abuf[q*ASTRIDE + kk], Wsb[kk], s);
    }
    s += __shfl_xor(s, 1, 64); s += __shfl_xor(s, 2, 64); s += __shfl_xor(s, 4, 64);

    float r3[3];
#pragma unroll
    for (int c2 = 0; c2 < 3; c2++){
      float rv = 0.f;
#pragma unroll
      for (int k = 0; k < 8; k++){
        int kk = part*8 + k;
        rv = fmaf((float)Qbuf[q*ASTRIDE + kk], Wrb[kk*3 + c2], rv);
      }
      rv += __shfl_xor(rv, 1, 64); rv += __shfl_xor(rv, 2, 64); rv += __shfl_xor(rv, 4, 64);
      r3[c2] = rv;
    }
    if (part == 0){
      size_t ob = ((size_t)(qbase + q)) * 4;
      out[ob + 0] = r3[0] + brb[0];
      out[ob + 1] = r3[1] + brb[1];
      out[ob + 2] = r3[2] + brb[2];
      out[ob + 3] = s + bsb[0];
    }
  }
}

// ---------------------------------------------------------------------------
extern "C" void kernel_launch(void* const* d_in, const int* in_sizes, int n_in,
                              void* d_out, int out_size, void* d_ws, size_t ws_size,
                              hipStream_t stream){
  (void)in_sizes; (void)n_in; (void)out_size; (void)ws_size;

  const int*   indices = (const int*)d_in[0];
  const float* qpts    = (const float*)d_in[1];
  const float* xyzdir  = (const float*)d_in[2];
  const float* cpos    = (const float*)d_in[3];
  const float* codes   = (const float*)d_in[4];
  const float* W0 = (const float*)d_in[5];
  const float* b0 = (const float*)d_in[6];
  const float* W1 = (const float*)d_in[7];
  const float* b1 = (const float*)d_in[8];
  const float* W2 = (const float*)d_in[9];
  const float* b2 = (const float*)d_in[10];
  const float* W3 = (const float*)d_in[11];
  const float* b3 = (const float*)d_in[12];
  const float* Wf = (const float*)d_in[13];
  const float* bf = (const float*)d_in[14];
  const float* Wd = (const float*)d_in[15];
  const float* bd = (const float*)d_in[16];
  const float* Ws = (const float*)d_in[17];
  const float* bs = (const float*)d_in[18];
  const float* Wr = (const float*)d_in[19];
  const float* br = (const float*)d_in[20];

  // ws layout (16-B aligned): Ain | Din | wt | cpos4
  half_t* Ain   = (half_t*)d_ws;                                   // 17,825,792 B
  half_t* Din   = (half_t*)((char*)d_ws + 17825792);               //  5,242,880 B
  half_t* wt    = (half_t*)((char*)d_ws + 17825792 + 5242880);     //    217,088 B
  float4* cpos4 = (float4*)((char*)d_ws + 17825792 + 5242880 + 217088);

  wtrans_kernel<<<(110592 + 255)/256, 256, 0, stream>>>(W0, W1, W2, W3, Wf, Wd,
                                                        indices, cpos, wt, cpos4);
  knn_kernel<<<N_Q/8, 512, 0, stream>>>(indices, qpts, cpos4, codes, xyzdir,
                                        Ain, Din);
  mlp_mfma<<<N_Q/64, 512, 0, stream>>>(Ain, Din, wt,
                                       b0, b1, b2, b3, bf, bd, Ws, bs, Wr, br,
                                       (float*)d_out);
}